// Round 4
// baseline (513.141 us; speedup 1.0000x reference)
//
#include <hip/hip_runtime.h>
#include <cstdint>
#include <cmath>

// ---------------------------------------------------------------------------
// RegionSelection on MI355X (gfx950) — R5: R4 (all-DMA split-f16 MFMA GEMMs)
// with the scratch-layout overlap FIXED via lifetime aliasing.
//
//   P0: split W1, W2 into u16 hi/lo planes ([n][k])
//   P1: split + transpose + TILE features into DMA-image planes (px-half)
//   K1: h1 = relu(W1 @ feat + b1): W and F both via global_load_lds (zero
//       staging VALU), dbuf, 1 barrier/iter. Epilogue emits h1 as tiled
//       split images (LDS bounce, coalesced). Two px-halves.
//   K2: h2 = relu(W2 @ h1 + b2): same kernel, F = h1 images, f32 out.
//   K3/K4/K5 unchanged.
//
// R4 bug: w1hi/w1lo/w2hi/w2lo regions overlapped (sized for u16 count/2,
// not /2 in float units) -> P0 cross-corrupted all weight planes.
// Fixed layout (float units), with h2 ALIASING the dead f-planes:
//   fhi  [0, 8388608)        flo [8388608, 16777216)   lifetime P1 -> K1
//   h2   [0, 8388608)                                  lifetime K2 -> K3
//   h1hi [16777216, 25165824) h1lo [25165824, 33554432) lifetime K1 -> K2
//   w1hi [33554432, 33816576) w1lo [33816576, 34078720)
//   w2hi [34078720, 34144256) w2lo [34144256, 34209792)
// max 34209792 < 42467328 (regions area, overwritten by K5 last).
//
// Numerics bit-identical to R3 (same split ops, same MFMA order):
// absmax must remain exactly 0.001953125.
// ---------------------------------------------------------------------------

typedef float f4 __attribute__((ext_vector_type(4)));
typedef _Float16 f16x8 __attribute__((ext_vector_type(8)));
typedef int i4 __attribute__((ext_vector_type(4)));
typedef unsigned short u16x4 __attribute__((ext_vector_type(4)));

#define M_PIX 32768
#define COORDS_OFF 42467328
#define ATT_OFF 42467712

#define FHI_OFF 0
#define FLO_OFF 8388608
#define H2_OFF 0                   // aliases f-planes (dead before K2)
#define H1HI_OFF 16777216
#define H1LO_OFF 25165824
#define W1HI_OFF 33554432
#define W1LO_OFF 33816576
#define W2HI_OFF 34078720
#define W2LO_OFF 34144256

#define GLOAD16(gp, lp) \
    __builtin_amdgcn_global_load_lds( \
        (const __attribute__((address_space(1))) unsigned int*)(gp), \
        (__attribute__((address_space(3))) unsigned int*)(lp), 16, 0, 0)

// swizzled int-index within an 8KB tile (128 rows x 16 ints = 32 f16/row).
// idx = (row*16 + k16/2) ^ ((row&7)<<2)  — bijective; HW-verified via the
// R3 W-DMA inverse. Inverse: row = (L>>4) ^ (((L>>4)>>2)&1);
//                            kint = (L&15) ^ ((row&3)<<2).
__device__ __forceinline__ int swz(int row, int k16) {
    return ((row << 4) + (k16 >> 1)) ^ ((row & 7) << 2);
}

__device__ __forceinline__ int split_pack(float v0, float v1, int& lop) {
    _Float16 h0 = (_Float16)v0, h1 = (_Float16)v1;
    float r0 = v0 - (float)h0, r1 = v1 - (float)h1;
    _Float16 l0 = (_Float16)r0, l1 = (_Float16)r1;
    unsigned int uh0 = __builtin_bit_cast(unsigned short, h0);
    unsigned int uh1 = __builtin_bit_cast(unsigned short, h1);
    unsigned int ul0 = __builtin_bit_cast(unsigned short, l0);
    unsigned int ul1 = __builtin_bit_cast(unsigned short, l1);
    lop = (int)(ul0 | (ul1 << 16));
    return (int)(uh0 | (uh1 << 16));
}

// ---------------------------------------------------------------------------
// P0: split a fp32 array into u16 hi/lo planes ([n][k] layout). n4 = count/4.
// ---------------------------------------------------------------------------
__global__ __launch_bounds__(256) void split_plane(
    const float* __restrict__ src, unsigned short* __restrict__ hi,
    unsigned short* __restrict__ lo, int n4)
{
    const int i = blockIdx.x * 256 + threadIdx.x;
    if (i >= n4) return;
    f4 v = *(const f4*)(src + 4 * (size_t)i);
    u16x4 hv, lv;
    #pragma unroll
    for (int j = 0; j < 4; ++j) {
        _Float16 h = (_Float16)v[j];
        _Float16 l = (_Float16)(v[j] - (float)h);
        hv[j] = __builtin_bit_cast(unsigned short, h);
        lv[j] = __builtin_bit_cast(unsigned short, l);
    }
    *(u16x4*)(hi + 4 * (size_t)i) = hv;
    *(u16x4*)(lo + 4 * (size_t)i) = lv;
}

// ---------------------------------------------------------------------------
// P1: features [32][1024][1024px] -> tiled split images.
// Block = one (local pb, kb) tile: reads 32 k x 128 px f32, splits,
// writes the swizzled 8KB hi and lo images contiguously.
// Grid: 4096 = 128 lpb x 32 kb.
// ---------------------------------------------------------------------------
__global__ __launch_bounds__(256) void split_tile_f(
    const float* __restrict__ feat, unsigned int* __restrict__ fhi,
    unsigned int* __restrict__ flo, int pb_base)
{
    const int blk = blockIdx.x;
    const int lpb = blk >> 5, kb = blk & 31;
    const int pb  = pb_base + lpb;
    const int t = threadIdx.x;
    __shared__ float ftile[32][128];

    // phase A: coalesced read of the 32k x 128px f32 tile
    const int k   = t >> 3;              // 0..31
    const int pxl = (t & 7) * 16;        // 0..112
    const int px0 = pb * 128;
    const size_t base = ((size_t)(px0 >> 10) << 20)
                      + (size_t)(kb * 32 + k) * 1024 + (px0 & 1023) + pxl;
    #pragma unroll
    for (int j = 0; j < 4; ++j)
        *(f4*)&ftile[k][pxl + 4 * j] = *(const f4*)(feat + base + 4 * j);
    __syncthreads();

    // phase B: thread t produces image ints [8t, 8t+8) (inverse-swizzle gather)
    const int L   = 8 * t;
    const int rL  = L >> 4;
    const int row = rL ^ ((rL >> 2) & 1);
    const int cb  = L & 15;              // 0 or 8
    unsigned int hp[8], lp[8];
    #pragma unroll
    for (int j = 0; j < 8; ++j) {
        const int kint = (cb + j) ^ ((row & 3) << 2);
        int lo;
        int hi = split_pack(ftile[2 * kint][row], ftile[2 * kint + 1][row], lo);
        hp[j] = (unsigned int)hi; lp[j] = (unsigned int)lo;
    }
    unsigned int* oh = fhi + (((size_t)lpb * 32 + kb) << 11) + L;
    unsigned int* ol = flo + (((size_t)lpb * 32 + kb) << 11) + L;
    *(i4*)(oh)     = *(i4*)&hp[0];
    *(i4*)(oh + 4) = *(i4*)&hp[4];
    *(i4*)(ol)     = *(i4*)&lp[0];
    *(i4*)(ol + 4) = *(i4*)&lp[4];
}

// ---------------------------------------------------------------------------
// GEMM: OUT = relu(W @ F + b). All staging via global_load_lds, dbuf,
// one barrier per k-iter. Block 128n x 128px, 4 waves (2x2), K_STEP 32.
// MODE 0 (K1): out = tiled split images (via LDS bounce).
// MODE 1 (K2): out = f32 [n][px].
// F tiles indexed by local pb (NKB tiles each); W from [n][k] u16 planes.
// ---------------------------------------------------------------------------
template<int MODE, int NBL, int NKB>
__global__ __launch_bounds__(256, 2) void gemm_mfma(
    const unsigned short* __restrict__ WH, const unsigned short* __restrict__ WL,
    const unsigned int* __restrict__ FH, const unsigned int* __restrict__ FL,
    const float* __restrict__ bias, void* __restrict__ OA, void* __restrict__ OB,
    int pb_base)
{
    constexpr int Kdim = NKB * 32;
    __shared__ int lds[16384];           // 64 KB: W dbuf [0,8192), F dbuf [8192,16384)

    const int t = threadIdx.x;
    const int lane = t & 63;
    const int wave = t >> 6;
    const int wn = wave >> 1, wp = wave & 1;

    // XCD remap: the (1<<NBL) n-blocks of one px-tile share blockid%8 -> XCD
    const int f   = blockIdx.x;
    const int nb  = (f >> 3) & ((1 << NBL) - 1);
    const int lpb = (f & 7) | ((f >> (3 + NBL)) << 3);
    const int n0  = nb * 128;
    const int px0 = (pb_base + lpb) * 128;

    // W DMA source pre-swizzle (R3-verified): instruction i covers LDS ints
    // [256i,256i+256); lane owns L=256i+4l..+3. Inverse of swz gives (r,c).
    int wg_off[2];
    #pragma unroll
    for (int j = 0; j < 2; ++j) {
        const int i  = 2 * wave + j;
        const int rL = 16 * i + (lane >> 2);
        const int r  = rL ^ ((rL >> 2) & 1);
        const int c  = (4 * (lane & 3)) ^ ((r & 3) << 2);
        wg_off[j] = (n0 + r) * Kdim + 2 * c;
    }

    // F DMA source: tiled images, fully linear. chunk i = 1KB at 256i.
    const unsigned int* fhb = FH + ((size_t)lpb * NKB << 11) + 256 * (2 * wave) + 4 * lane;
    const unsigned int* flb = FL + ((size_t)lpb * NKB << 11) + 256 * (2 * wave) + 4 * lane;

    f4 acc[4][4];
    #pragma unroll
    for (int i = 0; i < 4; ++i)
        #pragma unroll
        for (int j = 0; j < 4; ++j) acc[i][j] = (f4){0.f, 0.f, 0.f, 0.f};

    auto DMA = [&](int buf, int kb) {
        const int wb = buf * 4096, fb = 8192 + buf * 4096;
        const int k0 = kb * 32;
        #pragma unroll
        for (int j = 0; j < 2; ++j) {
            const int i = 2 * wave + j;
            GLOAD16(WH + wg_off[j] + k0, &lds[wb + 256 * i]);
            GLOAD16(WL + wg_off[j] + k0, &lds[wb + 2048 + 256 * i]);
            GLOAD16(fhb + ((size_t)kb << 11) + 256 * j, &lds[fb + 256 * i]);
            GLOAD16(flb + ((size_t)kb << 11) + 256 * j, &lds[fb + 2048 + 256 * i]);
        }
    };

    const int rA0 = 64 * wn + (lane & 15);
    const int rB0 = 64 * wp + (lane & 15);
    const int kg  = (lane >> 4) * 8;

    DMA(0, 0);
    int cur = 0;
    for (int kb = 0; kb < NKB; ++kb) {
        __syncthreads();   // drains DMA(cur); fences prev iter's reads of cur^1
        if (kb + 1 < NKB) DMA(cur ^ 1, kb + 1);   // in flight across MFMA phase

        const int wb = cur * 4096, fb = 8192 + cur * 4096;
        f16x8 bh[4], bl[4];
        #pragma unroll
        for (int nf = 0; nf < 4; ++nf) {
            bh[nf] = *(const f16x8*)&lds[fb + swz(rB0 + 16 * nf, kg)];
            bl[nf] = *(const f16x8*)&lds[fb + 2048 + swz(rB0 + 16 * nf, kg)];
        }
        #pragma unroll
        for (int m = 0; m < 4; ++m) {
            f16x8 ah = *(const f16x8*)&lds[wb + swz(rA0 + 16 * m, kg)];
            f16x8 al = *(const f16x8*)&lds[wb + 2048 + swz(rA0 + 16 * m, kg)];
            #pragma unroll
            for (int nf = 0; nf < 4; ++nf) {
                acc[m][nf] = __builtin_amdgcn_mfma_f32_16x16x32_f16(ah, bh[nf], acc[m][nf], 0, 0, 0);
                acc[m][nf] = __builtin_amdgcn_mfma_f32_16x16x32_f16(ah, bl[nf], acc[m][nf], 0, 0, 0);
                acc[m][nf] = __builtin_amdgcn_mfma_f32_16x16x32_f16(al, bh[nf], acc[m][nf], 0, 0, 0);
            }
        }
        cur ^= 1;
    }

    // C/D layout (HW-verified): col = lane&15, row = (lane>>4)*4 + reg
    if constexpr (MODE == 0) {
        // h1 -> tiled split images via LDS bounce (coalesced global writes).
        __syncthreads();
        #pragma unroll
        for (int m = 0; m < 4; ++m) {
            const int n_l = 64 * wn + 4 * (lane >> 4) + 16 * m;   // local n
            const f4 bv = *(const f4*)&bias[n0 + n_l];
            const int kb_l = n_l >> 5;
            #pragma unroll
            for (int nf = 0; nf < 4; ++nf) {
                const int row = 64 * wp + (lane & 15) + 16 * nf;  // local px
                float v0 = fmaxf(acc[m][nf][0] + bv[0], 0.0f);
                float v1 = fmaxf(acc[m][nf][1] + bv[1], 0.0f);
                float v2 = fmaxf(acc[m][nf][2] + bv[2], 0.0f);
                float v3 = fmaxf(acc[m][nf][3] + bv[3], 0.0f);
                int lo0, lo1;
                int hi0 = split_pack(v0, v1, lo0);
                int hi1 = split_pack(v2, v3, lo1);
                const int i0 = swz(row, (n_l & 31));
                const int i1 = swz(row, (n_l & 31) + 2);
                lds[kb_l * 2048 + i0]        = hi0;
                lds[kb_l * 2048 + i1]        = hi1;
                lds[8192 + kb_l * 2048 + i0] = lo0;
                lds[8192 + kb_l * 2048 + i1] = lo1;
            }
        }
        __syncthreads();
        // flat coalesced write-out: thread t -> 64 ints of tile g = t>>5
        const int g = t >> 5;                 // 0..7: plane g>>2, kb_l g&3
        const int l32 = t & 31;
        const int pb = pb_base + lpb;
        unsigned int* h1hi = (unsigned int*)OA;
        unsigned int* h1lo = (unsigned int*)OB;
        unsigned int* dst = ((g >> 2) ? h1lo : h1hi)
                          + (((size_t)pb * 16 + 4 * nb + (g & 3)) << 11) + 64 * l32;
        const int* src = &lds[(g >> 2) * 8192 + (g & 3) * 2048 + 64 * l32];
        #pragma unroll
        for (int q = 0; q < 16; ++q)
            *(i4*)(dst + 4 * q) = *(const i4*)(src + 4 * q);
    } else {
        float* o32 = (float*)OA;
        const int pxE = px0 + 64 * wp + (lane & 15);
        const int nE  = n0 + 64 * wn + 4 * (lane >> 4);
        #pragma unroll
        for (int m = 0; m < 4; ++m) {
            const int n_m = nE + 16 * m;
            const f4 bv = *(const f4*)&bias[n_m];
            #pragma unroll
            for (int nf = 0; nf < 4; ++nf) {
                const int p = pxE + 16 * nf;
                #pragma unroll
                for (int r = 0; r < 4; ++r)
                    o32[(size_t)(n_m + r) * M_PIX + p] = fmaxf(acc[m][nf][r] + bv[r], 0.0f);
            }
        }
    }
}

// ---------------------------------------------------------------------------
// K3: att[p] = (sigmoid(b3 + sum_k w3[k]*h2[k][p]) + cam[p]) * 0.5
// ---------------------------------------------------------------------------
__global__ __launch_bounds__(256) void layer3_att(
    const float* __restrict__ h2, const float* __restrict__ w3,
    const float* __restrict__ b3, const float* __restrict__ cam,
    float* __restrict__ att)
{
    const int p = blockIdx.x * 256 + threadIdx.x;
    float s = b3[0];
    #pragma unroll 8
    for (int k = 0; k < 256; ++k)
        s = fmaf(w3[k], h2[(size_t)k * M_PIX + p], s);
    const float sg = 1.0f / (1.0f + expf(-s));
    att[p] = (sg + cam[p]) * 0.5f;
}

// ---------------------------------------------------------------------------
// K4: per-batch 3x (argmax + suppression). 1 wave per batch.
// ---------------------------------------------------------------------------
__global__ __launch_bounds__(64) void peaks_kernel(
    const float* __restrict__ att, float* __restrict__ coords,
    int* __restrict__ wsyx)
{
    const int b = blockIdx.x;
    const int lane = threadIdx.x;
    __shared__ float s[1024];
    for (int i = lane; i < 1024; i += 64) s[i] = att[b * 1024 + i];
    __syncthreads();

    for (int kpk = 0; kpk < 3; ++kpk) {
        float bv = -1.0f;
        int bi = 0x7fffffff;
        for (int i = lane; i < 1024; i += 64) {
            float v = s[i];
            if (v > bv) { bv = v; bi = i; }
        }
        for (int off = 32; off >= 1; off >>= 1) {
            float ov = __shfl_down(bv, off);
            int   oi = __shfl_down(bi, off);
            if (ov > bv || (ov == bv && oi < bi)) { bv = ov; bi = oi; }
        }
        bv = __shfl(bv, 0);
        bi = __shfl(bi, 0);

        int fy, fx;
        if (bv > 0.0f) { fy = bi >> 5; fx = bi & 31; }
        else           { fy = 16;      fx = 16; }

        for (int i = lane; i < 1024; i += 64) {
            const int y = i >> 5, x = i & 31;
            const int dy = y > fy ? y - fy : fy - y;
            const int dx = x > fx ? x - fx : fx - x;
            if (dy <= 5 && dx <= 5) s[i] = 0.0f;
        }
        __syncthreads();

        if (lane == 0) {
            int y1 = fy * 16 - 192; y1 = y1 < 0 ? 0 : (y1 > 128 ? 128 : y1);
            int x1 = fx * 16 - 192; x1 = x1 < 0 ? 0 : (x1 > 128 ? 128 : x1);
            const int idx = b * 3 + kpk;
            coords[idx * 4 + 0] = (float)x1;
            coords[idx * 4 + 1] = (float)y1;
            coords[idx * 4 + 2] = (float)(x1 + 384);
            coords[idx * 4 + 3] = (float)(y1 + 384);
            wsyx[idx * 2 + 0] = y1;
            wsyx[idx * 2 + 1] = x1;
        }
        __syncthreads();
    }
}

// ---------------------------------------------------------------------------
// K5: crop 96 regions x 3ch x 384x384 (x1 is 16-float aligned).
// ---------------------------------------------------------------------------
__global__ __launch_bounds__(256) void crop_kernel(
    const float* __restrict__ orig, const int* __restrict__ wsyx,
    float* __restrict__ out)
{
    const int id = blockIdx.x * 256 + threadIdx.x;
    const int r    = id / (3 * 384 * 96);
    const int rem  = id - r * (3 * 384 * 96);
    const int c    = rem / (384 * 96);
    const int rem2 = rem - c * (384 * 96);
    const int row  = rem2 / 96;
    const int col  = (rem2 - row * 96) * 4;
    const int b = r / 3;
    const int y1 = wsyx[r * 2], x1 = wsyx[r * 2 + 1];
    const float* src = orig + (size_t)b * 786432 + (size_t)c * 262144
                     + (size_t)(y1 + row) * 512 + x1 + col;
    *(f4*)(out + (size_t)id * 4) = *(const f4*)src;
}

// ---------------------------------------------------------------------------
extern "C" void kernel_launch(void* const* d_in, const int* in_sizes, int n_in,
                              void* d_out, int out_size, void* d_ws, size_t ws_size,
                              hipStream_t stream)
{
    const float* features = (const float*)d_in[0];  // [32,1024,32,32]
    const float* cam      = (const float*)d_in[1];  // [32,32,32]
    const float* original = (const float*)d_in[2];  // [32,3,512,512]
    const float* w1 = (const float*)d_in[3];        // [512,1024]
    const float* b1 = (const float*)d_in[4];
    const float* w2 = (const float*)d_in[5];        // [256,512]
    const float* b2 = (const float*)d_in[6];
    const float* w3 = (const float*)d_in[7];        // [1,256]
    const float* b3 = (const float*)d_in[8];

    float* out = (float*)d_out;
    unsigned int* fhi  = (unsigned int*)(out + FHI_OFF);
    unsigned int* flo  = (unsigned int*)(out + FLO_OFF);
    unsigned int* h1hi = (unsigned int*)(out + H1HI_OFF);
    unsigned int* h1lo = (unsigned int*)(out + H1LO_OFF);
    float* h2 = out + H2_OFF;                       // aliases f-planes (dead)
    unsigned short* w1hi = (unsigned short*)(out + W1HI_OFF);
    unsigned short* w1lo = (unsigned short*)(out + W1LO_OFF);
    unsigned short* w2hi = (unsigned short*)(out + W2HI_OFF);
    unsigned short* w2lo = (unsigned short*)(out + W2LO_OFF);
    float* att    = out + ATT_OFF;
    float* coords = out + COORDS_OFF;
    int*   wsyx   = (int*)d_ws;

    dim3 b256(256);
    // P0: pre-split weights (w1: 524288 elts -> n4=131072; w2: n4=32768)
    split_plane<<<dim3(512), b256, 0, stream>>>(w1, w1hi, w1lo, 131072);
    split_plane<<<dim3(128), b256, 0, stream>>>(w2, w2hi, w2lo, 32768);
    // Half 0: P1 (px 0..16383) then K1 half
    split_tile_f<<<dim3(4096), b256, 0, stream>>>(features, fhi, flo, 0);
    gemm_mfma<0, 2, 32><<<dim3(512), b256, 0, stream>>>(
        w1hi, w1lo, fhi, flo, b1, h1hi, h1lo, 0);
    // Half 1: P1 (px 16384..32767) then K1 half
    split_tile_f<<<dim3(4096), b256, 0, stream>>>(features, fhi, flo, 128);
    gemm_mfma<0, 2, 32><<<dim3(512), b256, 0, stream>>>(
        w1hi, w1lo, fhi, flo, b1, h1hi, h1lo, 128);
    // K2: 256 x 32768, K=512, F = h1 tiled images, f32 out (over f-planes)
    gemm_mfma<1, 1, 16><<<dim3(512), b256, 0, stream>>>(
        w2hi, w2lo, h1hi, h1lo, b2, h2, nullptr, 0);
    // K3
    layer3_att<<<dim3(128), b256, 0, stream>>>(h2, w3, b3, cam, att);
    // K4
    peaks_kernel<<<dim3(32), dim3(64), 0, stream>>>(att, coords, wsyx);
    // K5
    crop_kernel<<<dim3(41472), b256, 0, stream>>>(original, wsyx, out);
}

// Round 5
// 451.258 us; speedup vs baseline: 1.1371x; 1.1371x over previous
//
#include <hip/hip_runtime.h>
#include <cstdint>
#include <cmath>

// ---------------------------------------------------------------------------
// RegionSelection on MI355X (gfx950) — R6: verified-pieces recombination.
//
//   P0: split W1, W2 into u16 hi/lo planes ([n][k])            (R3-verified)
//   K1: h1 = relu(W1 @ feat + b1). R3's loop (on-the-fly F split, W via
//       global_load_lds dbuf, 151us measured) + R5's tiled-image epilogue
//       (verified): h1 emitted as swizzled 8KB DMA images.
//   K2: h2 = relu(W2 @ h1 + b2). R5's all-DMA kernel (verified): W and F
//       both via global_load_lds, one barrier/iter. Replaces the
//       32-strided-scalar-loads/thread F-path (the hidden 150-250us sink).
//   K3/K4/K5 unchanged. NO P1 pre-pass (R5's net-negative piece).
//
// Numerics bit-identical to R1..R5: absmax must stay exactly 0.001953125.
//
// d_out scratch (float units):
//   h1hi [0, 8388608)         h1lo [8388608, 16777216)    K1 -> K2
//   h2   [16777216, 25165824)                             K2 -> K3
//   w1hi [25165824, 25427968) w1lo [25427968, 25690112)   P0 -> K1
//   w2hi [25690112, 25755648) w2lo [25755648, 25821184)   P0 -> K2
// max 25821184 < 42467328 (regions area, written last by K5).
// ---------------------------------------------------------------------------

typedef float f4 __attribute__((ext_vector_type(4)));
typedef _Float16 f16x8 __attribute__((ext_vector_type(8)));
typedef int i4 __attribute__((ext_vector_type(4)));
typedef unsigned short u16x4 __attribute__((ext_vector_type(4)));

#define M_PIX 32768
#define COORDS_OFF 42467328
#define ATT_OFF 42467712

#define H1HI_OFF 0
#define H1LO_OFF 8388608
#define H2_OFF 16777216
#define W1HI_OFF 25165824
#define W1LO_OFF 25427968
#define W2HI_OFF 25690112
#define W2LO_OFF 25755648

#define GLOAD16(gp, lp) \
    __builtin_amdgcn_global_load_lds( \
        (const __attribute__((address_space(1))) unsigned int*)(gp), \
        (__attribute__((address_space(3))) unsigned int*)(lp), 16, 0, 0)

// swizzled int-index within an 8KB tile (128 rows x 16 ints = 32 f16/row).
// idx = (row*16 + k16/2) ^ ((row&7)<<2). Bijective; HW-verified (R3 W-DMA).
// Inverse: row = (L>>4) ^ (((L>>4)>>2)&1); kint = (L&15) ^ ((row&3)<<2).
__device__ __forceinline__ int swz(int row, int k16) {
    return ((row << 4) + (k16 >> 1)) ^ ((row & 7) << 2);
}

__device__ __forceinline__ int split_pack(float v0, float v1, int& lop) {
    _Float16 h0 = (_Float16)v0, h1 = (_Float16)v1;
    float r0 = v0 - (float)h0, r1 = v1 - (float)h1;
    _Float16 l0 = (_Float16)r0, l1 = (_Float16)r1;
    unsigned int uh0 = __builtin_bit_cast(unsigned short, h0);
    unsigned int uh1 = __builtin_bit_cast(unsigned short, h1);
    unsigned int ul0 = __builtin_bit_cast(unsigned short, l0);
    unsigned int ul1 = __builtin_bit_cast(unsigned short, l1);
    lop = (int)(ul0 | (ul1 << 16));
    return (int)(uh0 | (uh1 << 16));
}

// ---------------------------------------------------------------------------
// P0: split a fp32 array into u16 hi/lo planes ([n][k] layout). n4 = count/4.
// ---------------------------------------------------------------------------
__global__ __launch_bounds__(256) void split_plane(
    const float* __restrict__ src, unsigned short* __restrict__ hi,
    unsigned short* __restrict__ lo, int n4)
{
    const int i = blockIdx.x * 256 + threadIdx.x;
    if (i >= n4) return;
    f4 v = *(const f4*)(src + 4 * (size_t)i);
    u16x4 hv, lv;
    #pragma unroll
    for (int j = 0; j < 4; ++j) {
        _Float16 h = (_Float16)v[j];
        _Float16 l = (_Float16)(v[j] - (float)h);
        hv[j] = __builtin_bit_cast(unsigned short, h);
        lv[j] = __builtin_bit_cast(unsigned short, l);
    }
    *(u16x4*)(hi + 4 * (size_t)i) = hv;
    *(u16x4*)(lo + 4 * (size_t)i) = lv;
}

// ---------------------------------------------------------------------------
// K1: h1 = relu(W1 @ feat + b1). Block 128n x 128px, 4 waves, K_STEP 32.
// W via global_load_lds (dbuf), F split on the fly (R3 structure, 151us).
// Epilogue: h1 -> tiled split images (R5-verified), coalesced write-out.
// Grid: 1024 = 4 nb x 256 pb, XCD-grouped.
// ---------------------------------------------------------------------------
__global__ __launch_bounds__(256, 2) void gemm_k1(
    const unsigned short* __restrict__ WH, const unsigned short* __restrict__ WL,
    const float* __restrict__ feat, const float* __restrict__ bias,
    unsigned int* __restrict__ OHI, unsigned int* __restrict__ OLO)
{
    constexpr int Kdim = 1024;
    // loop: W dbuf [0,8192) (buf*4096: hi +0, lo +2048), F hi 8192, lo 10240.
    // epilogue reuses all 16384 ints (64 KB).
    __shared__ int lds[16384];

    const int t = threadIdx.x;
    const int lane = t & 63;
    const int wave = t >> 6;
    const int wn = wave >> 1, wp = wave & 1;

    const int f  = blockIdx.x;
    const int nb = (f >> 3) & 3;
    const int pb = (f & 7) | ((f >> 5) << 3);
    const int n0  = nb * 128;
    const int px0 = pb * 128;

    const int rl = t & 127;          // F row (px) this thread stages
    const int kb = (t >> 7) * 16;    // k-half

    const float* F32 = feat + ((size_t)(px0 >> 10) << 20) + (px0 & 1023) + rl;

    // W DMA source pre-swizzle (R3-verified)
    int wg_off[2];
    #pragma unroll
    for (int j = 0; j < 2; ++j) {
        const int i  = 2 * wave + j;
        const int rL = 16 * i + (lane >> 2);
        const int r  = rL ^ ((rL >> 2) & 1);
        const int c  = (4 * (lane & 3)) ^ ((r & 3) << 2);
        wg_off[j] = (n0 + r) * Kdim + 2 * c;
    }

    f4 acc[4][4];
    #pragma unroll
    for (int i = 0; i < 4; ++i)
        #pragma unroll
        for (int j = 0; j < 4; ++j) acc[i][j] = (f4){0.f, 0.f, 0.f, 0.f};

    float fv[16];

    auto W_GLOADS = [&](int buf, int k0) {
        const int wb = buf * 4096;
        #pragma unroll
        for (int j = 0; j < 2; ++j) {
            const int i = 2 * wave + j;
            GLOAD16(WH + wg_off[j] + k0, &lds[wb + 256 * i]);
            GLOAD16(WL + wg_off[j] + k0, &lds[wb + 2048 + 256 * i]);
        }
    };
    auto LOADS_F = [&](int k0) {
        #pragma unroll
        for (int j = 0; j < 16; ++j)
            fv[j] = F32[(size_t)(k0 + kb + j) * 1024];
    };
    auto STAGE_F = [&]() {
        #pragma unroll
        for (int g = 0; g < 2; ++g) {
            i4 hp, lp;
            #pragma unroll
            for (int j = 0; j < 4; ++j) {
                int lo;
                hp[j] = split_pack(fv[8 * g + 2 * j], fv[8 * g + 2 * j + 1], lo);
                lp[j] = lo;
            }
            *(i4*)&lds[8192  + swz(rl, kb + 8 * g)] = hp;
            *(i4*)&lds[10240 + swz(rl, kb + 8 * g)] = lp;
        }
    };

    const int rA0 = 64 * wn + (lane & 15);
    const int rB0 = 64 * wp + (lane & 15);
    const int kg  = (lane >> 4) * 8;

    W_GLOADS(0, 0);
    LOADS_F(0);
    int cur = 0;
    for (int k0 = 0; k0 < Kdim; k0 += 32) {
        STAGE_F();
        __syncthreads();   // drains W DMA(cur) + F ds_writes
        if (k0 + 32 < Kdim) { W_GLOADS(cur ^ 1, k0 + 32); LOADS_F(k0 + 32); }

        const int wb = cur * 4096;
        f16x8 bh[4], bl[4];
        #pragma unroll
        for (int nf = 0; nf < 4; ++nf) {
            bh[nf] = *(const f16x8*)&lds[8192  + swz(rB0 + 16 * nf, kg)];
            bl[nf] = *(const f16x8*)&lds[10240 + swz(rB0 + 16 * nf, kg)];
        }
        #pragma unroll
        for (int m = 0; m < 4; ++m) {
            f16x8 ah = *(const f16x8*)&lds[wb + swz(rA0 + 16 * m, kg)];
            f16x8 al = *(const f16x8*)&lds[wb + 2048 + swz(rA0 + 16 * m, kg)];
            #pragma unroll
            for (int nf = 0; nf < 4; ++nf) {
                acc[m][nf] = __builtin_amdgcn_mfma_f32_16x16x32_f16(ah, bh[nf], acc[m][nf], 0, 0, 0);
                acc[m][nf] = __builtin_amdgcn_mfma_f32_16x16x32_f16(ah, bl[nf], acc[m][nf], 0, 0, 0);
                acc[m][nf] = __builtin_amdgcn_mfma_f32_16x16x32_f16(al, bh[nf], acc[m][nf], 0, 0, 0);
            }
        }
        __syncthreads();   // fences reads of cur before next STAGE_F / W write
        cur ^= 1;
    }

    // epilogue (R5-verified logic): h1 -> tiled split images via LDS bounce.
    // C/D layout: col(px) = lane&15, row(n) = (lane>>4)*4 + reg.
    #pragma unroll
    for (int m = 0; m < 4; ++m) {
        const int n_l = 64 * wn + 4 * (lane >> 4) + 16 * m;   // local n
        const f4 bv = *(const f4*)&bias[n0 + n_l];
        const int kb_l = n_l >> 5;
        #pragma unroll
        for (int nf = 0; nf < 4; ++nf) {
            const int row = 64 * wp + (lane & 15) + 16 * nf;  // local px
            float v0 = fmaxf(acc[m][nf][0] + bv[0], 0.0f);
            float v1 = fmaxf(acc[m][nf][1] + bv[1], 0.0f);
            float v2 = fmaxf(acc[m][nf][2] + bv[2], 0.0f);
            float v3 = fmaxf(acc[m][nf][3] + bv[3], 0.0f);
            int lo0, lo1;
            int hi0 = split_pack(v0, v1, lo0);
            int hi1 = split_pack(v2, v3, lo1);
            const int i0 = swz(row, (n_l & 31));
            const int i1 = swz(row, (n_l & 31) + 2);
            lds[kb_l * 2048 + i0]        = hi0;
            lds[kb_l * 2048 + i1]        = hi1;
            lds[8192 + kb_l * 2048 + i0] = lo0;
            lds[8192 + kb_l * 2048 + i1] = lo1;
        }
    }
    __syncthreads();
    // coalesced write-out: 8 groups (4 tiles x 2 planes) x 32 threads
    const int g = t >> 5;
    const int l32 = t & 31;
    unsigned int* dst = ((g >> 2) ? OLO : OHI)
                      + (((size_t)pb * 16 + 4 * nb + (g & 3)) << 11);
    const int* src = &lds[(g >> 2) * 8192 + (g & 3) * 2048];
    #pragma unroll
    for (int q = 0; q < 16; ++q)
        *(i4*)(dst + 128 * q + 4 * l32) = *(const i4*)(src + 128 * q + 4 * l32);
}

// ---------------------------------------------------------------------------
// K2: h2 = relu(W2 @ h1 + b2). R5-verified all-DMA kernel. NKB=16 (K=512).
// Grid: 512 = 2 nb x 256 pb, XCD-grouped. f32 out.
// ---------------------------------------------------------------------------
__global__ __launch_bounds__(256, 2) void gemm_k2(
    const unsigned short* __restrict__ WH, const unsigned short* __restrict__ WL,
    const unsigned int* __restrict__ FH, const unsigned int* __restrict__ FL,
    const float* __restrict__ bias, float* __restrict__ OUT)
{
    constexpr int NKB = 16;
    constexpr int Kdim = NKB * 32;
    __shared__ int lds[16384];   // W dbuf [0,8192), F dbuf [8192,16384)

    const int t = threadIdx.x;
    const int lane = t & 63;
    const int wave = t >> 6;
    const int wn = wave >> 1, wp = wave & 1;

    const int f   = blockIdx.x;
    const int nb  = (f >> 3) & 1;
    const int lpb = (f & 7) | ((f >> 4) << 3);
    const int n0  = nb * 128;
    const int px0 = lpb * 128;

    int wg_off[2];
    #pragma unroll
    for (int j = 0; j < 2; ++j) {
        const int i  = 2 * wave + j;
        const int rL = 16 * i + (lane >> 2);
        const int r  = rL ^ ((rL >> 2) & 1);
        const int c  = (4 * (lane & 3)) ^ ((r & 3) << 2);
        wg_off[j] = (n0 + r) * Kdim + 2 * c;
    }

    const unsigned int* fhb = FH + ((size_t)lpb * NKB << 11) + 256 * (2 * wave) + 4 * lane;
    const unsigned int* flb = FL + ((size_t)lpb * NKB << 11) + 256 * (2 * wave) + 4 * lane;

    f4 acc[4][4];
    #pragma unroll
    for (int i = 0; i < 4; ++i)
        #pragma unroll
        for (int j = 0; j < 4; ++j) acc[i][j] = (f4){0.f, 0.f, 0.f, 0.f};

    auto DMA = [&](int buf, int kbi) {
        const int wb = buf * 4096, fb = 8192 + buf * 4096;
        const int k0 = kbi * 32;
        #pragma unroll
        for (int j = 0; j < 2; ++j) {
            const int i = 2 * wave + j;
            GLOAD16(WH + wg_off[j] + k0, &lds[wb + 256 * i]);
            GLOAD16(WL + wg_off[j] + k0, &lds[wb + 2048 + 256 * i]);
            GLOAD16(fhb + ((size_t)kbi << 11) + 256 * j, &lds[fb + 256 * i]);
            GLOAD16(flb + ((size_t)kbi << 11) + 256 * j, &lds[fb + 2048 + 256 * i]);
        }
    };

    const int rA0 = 64 * wn + (lane & 15);
    const int rB0 = 64 * wp + (lane & 15);
    const int kg  = (lane >> 4) * 8;

    DMA(0, 0);
    int cur = 0;
    for (int kbi = 0; kbi < NKB; ++kbi) {
        __syncthreads();   // drains DMA(cur); fences prev reads of cur^1
        if (kbi + 1 < NKB) DMA(cur ^ 1, kbi + 1);

        const int wb = cur * 4096, fb = 8192 + cur * 4096;
        f16x8 bh[4], bl[4];
        #pragma unroll
        for (int nf = 0; nf < 4; ++nf) {
            bh[nf] = *(const f16x8*)&lds[fb + swz(rB0 + 16 * nf, kg)];
            bl[nf] = *(const f16x8*)&lds[fb + 2048 + swz(rB0 + 16 * nf, kg)];
        }
        #pragma unroll
        for (int m = 0; m < 4; ++m) {
            f16x8 ah = *(const f16x8*)&lds[wb + swz(rA0 + 16 * m, kg)];
            f16x8 al = *(const f16x8*)&lds[wb + 2048 + swz(rA0 + 16 * m, kg)];
            #pragma unroll
            for (int nf = 0; nf < 4; ++nf) {
                acc[m][nf] = __builtin_amdgcn_mfma_f32_16x16x32_f16(ah, bh[nf], acc[m][nf], 0, 0, 0);
                acc[m][nf] = __builtin_amdgcn_mfma_f32_16x16x32_f16(ah, bl[nf], acc[m][nf], 0, 0, 0);
                acc[m][nf] = __builtin_amdgcn_mfma_f32_16x16x32_f16(al, bh[nf], acc[m][nf], 0, 0, 0);
            }
        }
        cur ^= 1;
    }

    const int pxE = px0 + 64 * wp + (lane & 15);
    const int nE  = n0 + 64 * wn + 4 * (lane >> 4);
    #pragma unroll
    for (int m = 0; m < 4; ++m) {
        const int n_m = nE + 16 * m;
        const f4 bv = *(const f4*)&bias[n_m];
        #pragma unroll
        for (int nf = 0; nf < 4; ++nf) {
            const int p = pxE + 16 * nf;
            #pragma unroll
            for (int r = 0; r < 4; ++r)
                OUT[(size_t)(n_m + r) * M_PIX + p] = fmaxf(acc[m][nf][r] + bv[r], 0.0f);
        }
    }
}

// ---------------------------------------------------------------------------
// K3: att[p] = (sigmoid(b3 + sum_k w3[k]*h2[k][p]) + cam[p]) * 0.5
// ---------------------------------------------------------------------------
__global__ __launch_bounds__(256) void layer3_att(
    const float* __restrict__ h2, const float* __restrict__ w3,
    const float* __restrict__ b3, const float* __restrict__ cam,
    float* __restrict__ att)
{
    const int p = blockIdx.x * 256 + threadIdx.x;
    float s = b3[0];
    #pragma unroll 8
    for (int k = 0; k < 256; ++k)
        s = fmaf(w3[k], h2[(size_t)k * M_PIX + p], s);
    const float sg = 1.0f / (1.0f + expf(-s));
    att[p] = (sg + cam[p]) * 0.5f;
}

// ---------------------------------------------------------------------------
// K4: per-batch 3x (argmax + suppression). 1 wave per batch.
// ---------------------------------------------------------------------------
__global__ __launch_bounds__(64) void peaks_kernel(
    const float* __restrict__ att, float* __restrict__ coords,
    int* __restrict__ wsyx)
{
    const int b = blockIdx.x;
    const int lane = threadIdx.x;
    __shared__ float s[1024];
    for (int i = lane; i < 1024; i += 64) s[i] = att[b * 1024 + i];
    __syncthreads();

    for (int kpk = 0; kpk < 3; ++kpk) {
        float bv = -1.0f;
        int bi = 0x7fffffff;
        for (int i = lane; i < 1024; i += 64) {
            float v = s[i];
            if (v > bv) { bv = v; bi = i; }
        }
        for (int off = 32; off >= 1; off >>= 1) {
            float ov = __shfl_down(bv, off);
            int   oi = __shfl_down(bi, off);
            if (ov > bv || (ov == bv && oi < bi)) { bv = ov; bi = oi; }
        }
        bv = __shfl(bv, 0);
        bi = __shfl(bi, 0);

        int fy, fx;
        if (bv > 0.0f) { fy = bi >> 5; fx = bi & 31; }
        else           { fy = 16;      fx = 16; }

        for (int i = lane; i < 1024; i += 64) {
            const int y = i >> 5, x = i & 31;
            const int dy = y > fy ? y - fy : fy - y;
            const int dx = x > fx ? x - fx : fx - x;
            if (dy <= 5 && dx <= 5) s[i] = 0.0f;
        }
        __syncthreads();

        if (lane == 0) {
            int y1 = fy * 16 - 192; y1 = y1 < 0 ? 0 : (y1 > 128 ? 128 : y1);
            int x1 = fx * 16 - 192; x1 = x1 < 0 ? 0 : (x1 > 128 ? 128 : x1);
            const int idx = b * 3 + kpk;
            coords[idx * 4 + 0] = (float)x1;
            coords[idx * 4 + 1] = (float)y1;
            coords[idx * 4 + 2] = (float)(x1 + 384);
            coords[idx * 4 + 3] = (float)(y1 + 384);
            wsyx[idx * 2 + 0] = y1;
            wsyx[idx * 2 + 1] = x1;
        }
        __syncthreads();
    }
}

// ---------------------------------------------------------------------------
// K5: crop 96 regions x 3ch x 384x384 (x1 is 16-float aligned).
// ---------------------------------------------------------------------------
__global__ __launch_bounds__(256) void crop_kernel(
    const float* __restrict__ orig, const int* __restrict__ wsyx,
    float* __restrict__ out)
{
    const int id = blockIdx.x * 256 + threadIdx.x;
    const int r    = id / (3 * 384 * 96);
    const int rem  = id - r * (3 * 384 * 96);
    const int c    = rem / (384 * 96);
    const int rem2 = rem - c * (384 * 96);
    const int row  = rem2 / 96;
    const int col  = (rem2 - row * 96) * 4;
    const int b = r / 3;
    const int y1 = wsyx[r * 2], x1 = wsyx[r * 2 + 1];
    const float* src = orig + (size_t)b * 786432 + (size_t)c * 262144
                     + (size_t)(y1 + row) * 512 + x1 + col;
    *(f4*)(out + (size_t)id * 4) = *(const f4*)src;
}

// ---------------------------------------------------------------------------
extern "C" void kernel_launch(void* const* d_in, const int* in_sizes, int n_in,
                              void* d_out, int out_size, void* d_ws, size_t ws_size,
                              hipStream_t stream)
{
    const float* features = (const float*)d_in[0];  // [32,1024,32,32]
    const float* cam      = (const float*)d_in[1];  // [32,32,32]
    const float* original = (const float*)d_in[2];  // [32,3,512,512]
    const float* w1 = (const float*)d_in[3];        // [512,1024]
    const float* b1 = (const float*)d_in[4];
    const float* w2 = (const float*)d_in[5];        // [256,512]
    const float* b2 = (const float*)d_in[6];
    const float* w3 = (const float*)d_in[7];        // [1,256]
    const float* b3 = (const float*)d_in[8];

    float* out = (float*)d_out;
    unsigned int* h1hi = (unsigned int*)(out + H1HI_OFF);
    unsigned int* h1lo = (unsigned int*)(out + H1LO_OFF);
    float* h2 = out + H2_OFF;
    unsigned short* w1hi = (unsigned short*)(out + W1HI_OFF);
    unsigned short* w1lo = (unsigned short*)(out + W1LO_OFF);
    unsigned short* w2hi = (unsigned short*)(out + W2HI_OFF);
    unsigned short* w2lo = (unsigned short*)(out + W2LO_OFF);
    float* att    = out + ATT_OFF;
    float* coords = out + COORDS_OFF;
    int*   wsyx   = (int*)d_ws;

    dim3 b256(256);
    // P0: pre-split weights
    split_plane<<<dim3(512), b256, 0, stream>>>(w1, w1hi, w1lo, 131072);
    split_plane<<<dim3(128), b256, 0, stream>>>(w2, w2hi, w2lo, 32768);
    // K1: 512 x 32768, K=1024 -> h1 tiled split images
    gemm_k1<<<dim3(1024), b256, 0, stream>>>(w1hi, w1lo, features, b1, h1hi, h1lo);
    // K2: 256 x 32768, K=512, all-DMA from h1 images -> h2 f32
    gemm_k2<<<dim3(512), b256, 0, stream>>>(w2hi, w2lo, h1hi, h1lo, b2, h2);
    // K3
    layer3_att<<<dim3(128), b256, 0, stream>>>(h2, w3, b3, cam, att);
    // K4
    peaks_kernel<<<dim3(32), dim3(64), 0, stream>>>(att, coords, wsyx);
    // K5
    crop_kernel<<<dim3(41472), b256, 0, stream>>>(original, wsyx, out);
}